// Round 16
// baseline (2701.676 us; speedup 1.0000x reference)
//
#include <hip/hip_runtime.h>

#define VN 512
#define EN 32768
#define FN 8
#define HN 128
#define G3 384
#define LN 3
#define TP 16
#define NROWS (VN*VN)   // 262144
#define XIPAD 388       // 4*388 % 32 == 16 -> 2-way LDS aliasing (free)

typedef _Float16 f16x8 __attribute__((ext_vector_type(8)));
typedef float f32x4  __attribute__((ext_vector_type(4)));

__device__ __forceinline__ unsigned short f2h(float f) {
    _Float16 h = (_Float16)f;
    return __builtin_bit_cast(unsigned short, h);
}
__device__ __forceinline__ float h2f(unsigned short u) {
    return (float)__builtin_bit_cast(_Float16, u);
}
__device__ __forceinline__ float fexp2(float x) {
    float r; asm("v_exp_f32 %0, %1" : "=v"(r) : "v"(x)); return r;
}
__device__ __forceinline__ float frcp(float x) {
    float r; asm("v_rcp_f32 %0, %1" : "=v"(r) : "v"(x)); return r;
}
__device__ __forceinline__ float fsigmoid(float x) {
    return frcp(1.f + fexp2(x * -1.44269504089f));
}
__device__ __forceinline__ float ftanh(float x) {
    return 1.f - 2.f * frcp(1.f + fexp2(x * 2.88539008178f));
}

// ---------------- generic int fill ----------------
__global__ void k_fill(int* __restrict__ p, int val, int n) {
    int i = blockIdx.x * 256 + threadIdx.x;
    if (i < n) p[i] = val;
}

// ---------------- edge canonicalize (+ int64 detection) ----------------
__global__ void k_edges(const void* __restrict__ raw, int* __restrict__ uo, int* __restrict__ vo) {
    const int* r32 = (const int*)raw;
    const long long* r64 = (const long long*)raw;
    int acc = 0;
    #pragma unroll
    for (int i = 1; i < 128; i += 2) acc |= r32[i];
    bool is64 = (acc == 0);
    int e = blockIdx.x * 256 + threadIdx.x;
    if (e < EN) {
        int u, v;
        if (is64) { u = (int)r64[2*e]; v = (int)r64[2*e+1]; }
        else      { u = r32[2*e];      v = r32[2*e+1]; }
        uo[e] = u; vo[e] = v;
    }
}

// ---------------- pack weight B-fragments (single f16, MFMA lane layout) ----------------
// frag layout: [..ntile..][ktile][lane][elem]: k = kt*32 + (lane>>4)*8 + e ; col = nt*16 + (lane&15)
__global__ void k_pack(const float* __restrict__ w1, const float* __restrict__ w2,
                       const float* __restrict__ w3, const float* __restrict__ wih,
                       const float* __restrict__ whh,
                       unsigned short* __restrict__ wsF, unsigned short* __restrict__ whF,
                       unsigned short* __restrict__ wlF, unsigned short* __restrict__ wcF) {
    int t = blockIdx.x * 256 + threadIdx.x;
    if (t < 3*8*12*64*8) {        // wcat frags [l][nt0..7][kt0..11]
        int e = t & 7, lane = (t >> 3) & 63;
        int frag = t >> 9;
        int kt = frag % 12;
        int rem = frag / 12;
        int nt = rem & 7;
        int l  = rem >> 3;
        int k  = kt*32 + (lane >> 4)*8 + e;
        int gc = nt*16 + (lane & 15);
        const float* w = (k < 128) ? w1 : (k < 256 ? w2 : w3);
        wcF[t] = f2h(w[((long)l*128 + gc)*128 + (k & 127)]);
    }
    if (t < 24*4*64*8) {          // wsum / whh / wl frags [nt0..23][kt0..3]
        int e = t & 7, lane = (t >> 3) & 63, kt = (t >> 9) & 3, nt = t >> 11;
        int k  = kt*32 + (lane >> 4)*8 + e;
        int gc = nt*16 + (lane & 15);
        wsF[t] = f2h(wih[gc*256 + k] + wih[gc*256 + 128 + k]);
        whF[t] = f2h(whh[gc*HN + k]);
        wlF[t] = f2h(wih[gc*256 + k]);
    }
}

// ---------------- winner map ----------------
__global__ void k_map(const int* __restrict__ uA, const int* __restrict__ vA, int* __restrict__ map) {
    int e = blockIdx.x * 256 + threadIdx.x;
    if (e < EN) atomicMax(&map[uA[e]*VN + vA[e]], e);
}

// ---------------- embed ----------------
__global__ __launch_bounds__(256) void k_embed(const float* __restrict__ adj,
                                               const float* __restrict__ emb,
                                               float* __restrict__ x) {
    __shared__ float semb[HN][FN];
    __shared__ float sadj[2][FN];
    int tid = threadIdx.x;
    for (int i = tid; i < HN*FN; i += 256) semb[i/FN][i%FN] = emb[i];
    if (tid < 16) sadj[tid>>3][tid&7] = adj[(long)blockIdx.x*16 + tid];
    __syncthreads();
    int p = tid >> 7;
    int h = tid & 127;
    float acc = 0.f;
    #pragma unroll
    for (int f = 0; f < FN; f++) acc += sadj[p][f]*semb[h][f];
    long row = (long)blockIdx.x*2 + p;
    x[row*HN + h] = acc;
}

// ---------------- colsum + nnz ----------------
__global__ __launch_bounds__(512) void k_colsum(const float* __restrict__ x,
                                                float* __restrict__ colsum, int* __restrict__ nnz) {
    int b = blockIdx.x;
    int tid = threadIdx.x;
    int h = tid & 127, q = tid >> 7;
    float s = 0.f; int c = 0;
    for (int a = q*128; a < q*128 + 128; a++) {
        float v = x[((long)a*VN + b)*HN + h];
        s += v; c += (v != 0.f) ? 1 : 0;
    }
    __shared__ float ss[4][128];
    __shared__ int sc[8];
    ss[q][h] = s;
    #pragma unroll
    for (int off = 32; off; off >>= 1) c += __shfl_down(c, off);
    if ((tid & 63) == 0) sc[tid>>6] = c;
    __syncthreads();
    if (tid < 128) colsum[b*HN + tid] = ss[0][tid]+ss[1][tid]+ss[2][tid]+ss[3][tid];
    if (tid == 0) { int t = 0; for (int i = 0; i < 8; i++) t += sc[i]; nnz[b] = t; }
}

// ---------------- edge inputs ----------------
__global__ __launch_bounds__(256) void k_edgein(const float* __restrict__ x,
    const int* __restrict__ uA, const int* __restrict__ vA,
    const float* __restrict__ colsum, const int* __restrict__ nnz, float* __restrict__ in3) {
    int w = threadIdx.x >> 6;
    int lane = threadIdx.x & 63;
    int e = blockIdx.x*4 + w;
    int u = uA[e], v = vA[e];
    const float* xuv = x + ((long)u*VN + v)*HN;
    const float* xvu = x + ((long)v*VN + u)*HN;
    float xu0 = xuv[lane], xu1 = xuv[lane+64];
    float xv0 = xvu[lane], xv1 = xvu[lane+64];
    int cnt_vu = __popcll(__ballot(xv0 != 0.f)) + __popcll(__ballot(xv1 != 0.f));
    int cnt_uv = __popcll(__ballot(xu0 != 0.f)) + __popcll(__ballot(xu1 != 0.f));
    float nin  = (float)(nnz[u] - cnt_vu) * (1.f/128.f); if (nin  == 0.f) nin  = 1.f;
    float nout = (float)(nnz[v] - cnt_uv) * (1.f/128.f); if (nout == 0.f) nout = 1.f;
    float* o = in3 + (long)e*G3;
    o[lane]        = xu0;  o[lane+64]      = xu1;
    o[128+lane]    = (colsum[u*HN+lane]    - xv0)/nin;
    o[128+lane+64] = (colsum[u*HN+lane+64] - xv1)/nin;
    o[256+lane]    = (colsum[v*HN+lane]    - xu0)/nout;
    o[256+lane+64] = (colsum[v*HN+lane+64] - xu1)/nout;
}

#define MF16(A,B,C) __builtin_amdgcn_mfma_f32_16x16x32_f16((A),(B),(C),0,0,0)
#define Z4 ((f32x4){0.f,0.f,0.f,0.f})

// ---------------- fused msg+corr (f16 MFMA) ----------------
__global__ __launch_bounds__(512) void k_msgcorr(
    const float* __restrict__ in3,
    const unsigned short* __restrict__ wcF, const unsigned short* __restrict__ wlF,
    float* __restrict__ corr) {
    const int g = threadIdx.x;
    const int wv = g >> 6;
    const int lane = g & 63;
    const int r16 = lane & 15;
    const int kgrp = lane >> 4;
    const long m0 = (long)blockIdx.x * 16;

    __shared__ unsigned short Dh[16][136];
    __shared__ unsigned short Dl[16][136];

    f32x4 pacc[2];
    pacc[0] = Z4; pacc[1] = Z4;
    #pragma unroll
    for (int kt = 0; kt < 12; kt++) {
        const float* xs = &in3[(m0 + r16)*G3 + kt*32 + kgrp*8];
        float4 v0 = *(const float4*)xs;
        float4 v1 = *(const float4*)(xs + 4);
        float vv[8] = {v0.x,v0.y,v0.z,v0.w,v1.x,v1.y,v1.z,v1.w};
        f16x8 H, L;
        #pragma unroll
        for (int j = 0; j < 8; j++) {
            _Float16 h = (_Float16)vv[j];
            H[j] = h;
            L[j] = (_Float16)(vv[j] - (float)h);
        }
        f16x8 bF = *(const f16x8*)&wcF[(((long)wv*12 + kt)*64 + lane)*8];
        const int p = kt & 1;
        pacc[p] = MF16(H, bF, pacc[p]);
        pacc[p] = MF16(L, bF, pacc[p]);
    }
    const int c = wv*16 + r16;
    #pragma unroll
    for (int r = 0; r < 4; r++) {
        int m = kgrp*4 + r;
        float mv = fmaxf(pacc[0][r] + pacc[1][r], 0.f) - in3[(m0 + m)*G3 + c];
        unsigned short hi = f2h(mv);
        Dh[m][c] = hi;
        Dl[m][c] = f2h(mv - h2f(hi));
    }
    __syncthreads();

    f32x4 cacc[3];
    cacc[0] = cacc[1] = cacc[2] = Z4;
    #pragma unroll
    for (int kt = 0; kt < 4; kt++) {
        f16x8 ah = *(const f16x8*)&Dh[r16][kt*32 + kgrp*8];
        f16x8 al = *(const f16x8*)&Dl[r16][kt*32 + kgrp*8];
        #pragma unroll
        for (int j = 0; j < 3; j++) {
            f16x8 bF = *(const f16x8*)&wlF[(((long)(wv*3 + j)*4 + kt)*64 + lane)*8];
            cacc[j] = MF16(ah, bF, cacc[j]);
            cacc[j] = MF16(al, bF, cacc[j]);
        }
    }
    #pragma unroll
    for (int j = 0; j < 3; j++) {
        int n = (wv*3 + j)*16 + r16;
        #pragma unroll
        for (int r = 0; r < 4; r++)
            corr[(m0 + kgrp*4 + r)*G3 + n] = cacc[j][r];
    }
}

// ================= fused xi(f16 MFMA, phase-A) + GRU scan (v14) =================
// 256 blocks x 512 threads (8 waves); block owns chains {a0, a0+256}.
// Register diet vs v13: (1) gh uses 3 accumulators (gr/gz/gn, 4-deep chains),
// (2) phase-A xi split per chain (3 accumulators reused), peak unified
// (arch+accum) ~115 <= 128. __launch_bounds__(512,4) pins the 128 budget so
// two 8-wave blocks co-reside per CU (r12's clamp failed because the live set
// was ~160 then; it fits now). Spill signature to watch: FETCH_SIZE explosion.

// stage x rows [ROWBASE, ROWBASE+16) of both chains into xS (f16 hi, 4-bit XOR swizzle)
#define STAGE(ROWBASE) do { \
    int rs_ = g >> 8, row_ = (g >> 4) & 15, cg_ = g & 15; \
    const float* xs_ = &x[((long)(a0 + rs_*256)*VN + (ROWBASE) + row_)*HN + cg_*8]; \
    float4 v0_ = *(const float4*)xs_; \
    float4 v1_ = *(const float4*)(xs_ + 4); \
    f16x8 H_; \
    H_[0] = (_Float16)v0_.x; H_[1] = (_Float16)v0_.y; \
    H_[2] = (_Float16)v0_.z; H_[3] = (_Float16)v0_.w; \
    H_[4] = (_Float16)v1_.x; H_[5] = (_Float16)v1_.y; \
    H_[6] = (_Float16)v1_.z; H_[7] = (_Float16)v1_.w; \
    int slot_ = cg_ ^ row_; \
    *(f16x8*)&xSh[rs_][row_][slot_*8] = H_; \
} while(0)

#define XB(GI,KT) (*(const f16x8*)&wsF[(((long)((GI)*8 + wv)*4 + (KT))*64 + lane)*8])
#define XA(RS,KT) (*(const f16x8*)&xSh[RS][r16][((((KT)*4 + kgrp) ^ r16)*8)])

// xi for one chain: 4 A-frags preloaded, 3 accumulators, 12 MFMA, store w/ bias
#define XI_CHAIN(RS) do { \
    f16x8 xA0_ = XA(RS,0), xA1_ = XA(RS,1), xA2_ = XA(RS,2), xA3_ = XA(RS,3); \
    f32x4 aR_ = Z4, aZ_ = Z4, aN_ = Z4; \
    aR_ = MF16(xA0_, XB(0,0), aR_); \
    aZ_ = MF16(xA0_, XB(1,0), aZ_); \
    aN_ = MF16(xA0_, XB(2,0), aN_); \
    aR_ = MF16(xA1_, XB(0,1), aR_); \
    aZ_ = MF16(xA1_, XB(1,1), aZ_); \
    aN_ = MF16(xA1_, XB(2,1), aN_); \
    aR_ = MF16(xA2_, XB(0,2), aR_); \
    aZ_ = MF16(xA2_, XB(1,2), aZ_); \
    aN_ = MF16(xA2_, XB(2,2), aN_); \
    aR_ = MF16(xA3_, XB(0,3), aR_); \
    aZ_ = MF16(xA3_, XB(1,3), aZ_); \
    aN_ = MF16(xA3_, XB(2,3), aN_); \
    _Pragma("unroll") \
    for (int r_ = 0; r_ < 4; ++r_) { \
        xiP[RS][kgrp*4 + r_][c]        = aR_[r_] + biR; \
        xiP[RS][kgrp*4 + r_][HN + c]   = aZ_[r_] + biZ; \
        xiP[RS][kgrp*4 + r_][2*HN + c] = aN_[r_] + biN; \
    } \
} while(0)

#define CORR_ADD() do { if (g < G3) { \
    for (int rs_ = 0; rs_ < 2; ++rs_) \
        for (int t_ = 0; t_ < TP; ++t_) { \
            int e_ = eS[rs_][t_]; \
            if (e_ >= 0) xiP[rs_][t_][g] += corr[(long)e_*G3 + g]; \
        } } } while(0)

#define STEP(T) do { \
    const int arow_ = r16 & 1; \
    f16x8 hA0_ = *(const f16x8*)&hSh[cur][arow_][0*32 + kgrp*8]; \
    f16x8 hA1_ = *(const f16x8*)&hSh[cur][arow_][1*32 + kgrp*8]; \
    f16x8 hA2_ = *(const f16x8*)&hSh[cur][arow_][2*32 + kgrp*8]; \
    f16x8 hA3_ = *(const f16x8*)&hSh[cur][arow_][3*32 + kgrp*8]; \
    f32x4 gr_ = Z4, gz_ = Z4, gn_ = Z4; \
    __builtin_amdgcn_s_setprio(1); \
    gr_ = MF16(hA0_, wH[0], gr_); \
    gz_ = MF16(hA0_, wH[4], gz_); \
    gn_ = MF16(hA0_, wH[8], gn_); \
    gr_ = MF16(hA1_, wH[1], gr_); \
    gz_ = MF16(hA1_, wH[5], gz_); \
    gn_ = MF16(hA1_, wH[9], gn_); \
    gr_ = MF16(hA2_, wH[2], gr_); \
    gz_ = MF16(hA2_, wH[6], gz_); \
    gn_ = MF16(hA2_, wH[10], gn_); \
    gr_ = MF16(hA3_, wH[3], gr_); \
    gz_ = MF16(hA3_, wH[7], gz_); \
    gn_ = MF16(hA3_, wH[11], gn_); \
    __builtin_amdgcn_s_setprio(0); \
    float sR_ = gr_[0], tR_ = gr_[1]; \
    float sZ_ = gz_[0], tZ_ = gz_[1]; \
    float sN_ = gn_[0], tN_ = gn_[1]; \
    float mR_ = __int_as_float(__builtin_amdgcn_ds_swizzle(__float_as_int(tR_), 0x401F)); \
    float mZ_ = __int_as_float(__builtin_amdgcn_ds_swizzle(__float_as_int(tZ_), 0x401F)); \
    float mN_ = __int_as_float(__builtin_amdgcn_ds_swizzle(__float_as_int(tN_), 0x401F)); \
    float vR_ = (lane < 16) ? sR_ : mR_; \
    float vZ_ = (lane < 16) ? sZ_ : mZ_; \
    float vN_ = (lane < 16) ? sN_ : mN_; \
    if (lane < 32) { \
        int rs_ = lane >> 4; \
        float xr_ = xiP[rs_][T][c]; \
        float xz_ = xiP[rs_][T][HN + c]; \
        float xn_ = xiP[rs_][T][2*HN + c]; \
        float r_ = fsigmoid(xr_ + vR_ + br); \
        float z_ = fsigmoid(xz_ + vZ_ + bz); \
        float n_ = ftanh(xn_ + r_*(vN_ + bn)); \
        float h_ = (1.f - z_)*n_ + z_*hprev; \
        hprev = h_; \
        hOut[rs_][T][c] = h_; \
        hSh[cur ^ 1][rs_][c] = f2h(h_); \
    } \
    cur ^= 1; \
    __syncthreads(); \
} while(0)

__global__ __launch_bounds__(512, 4) void k_scanf(
    float* __restrict__ x,
    const unsigned short* __restrict__ wsF, const unsigned short* __restrict__ whF,
    const float* __restrict__ bih, const float* __restrict__ bhh,
    const float* __restrict__ corr, const int* __restrict__ map) {
    const int g = threadIdx.x;
    const int a0 = blockIdx.x;
    const int wv = g >> 6;
    const int lane = g & 63;
    const int r16 = lane & 15;
    const int kgrp = lane >> 4;

    __shared__ float xiP[2][TP][XIPAD];             // 49.7 KB [chain][t][col3]
    __shared__ unsigned short xSh[2][TP][HN];       // 8 KB (chain, row, swz col) -- hi only
    __shared__ unsigned short hSh[2][2][HN];        // [parity][chain][col] 1 KB -- f16 single
    __shared__ float hOut[2][TP][HN];               // 16 KB
    __shared__ int eS[2][TP];                       // total ~74.9 KB -> 2 blocks/CU

    // resident whh B-frags only (48 VGPRs); wsF streamed in phase A
    f16x8 wH[12];
    #pragma unroll
    for (int gi = 0; gi < 3; gi++)
        #pragma unroll
        for (int kt = 0; kt < 4; kt++) {
            long bidx = (((long)(gi*8 + wv)*4 + kt)*64 + lane)*8;
            wH[gi*4+kt] = *(const f16x8*)&whF[bidx];
        }

    const int c = wv*16 + r16;
    const float br = bhh[c],  bz = bhh[HN + c],  bn = bhh[2*HN + c];
    const float biR = bih[c], biZ = bih[HN + c], biN = bih[2*HN + c];
    float hprev = 0.f;                  // lanes<32: chain (lane>>4)

    if (g < 2*HN) ((unsigned short*)hSh)[g] = 0;
    int cur = 0;

    // ---- prologue: stage panel 0 ----
    STAGE(0);
    __syncthreads();

    for (int p0 = 0; p0 < VN; p0 += TP) {
        const bool hasnext = (p0 + TP) < VN;

        // ---- phase A region 1: writeback(p-1), eS(p), xi(p) from xS (B-frags from L2) ----
        if (p0 > 0) {
            int pp = p0 - TP;
            for (int idx = g; idx < 2*TP*32; idx += 512) {
                int rs = idx >> 9, j = idx & 511, t = j >> 5, c4 = j & 31;
                *(float4*)&x[((long)(a0 + rs*256)*VN + pp + t)*HN + c4*4] =
                    *(const float4*)&hOut[rs][t][c4*4];
            }
        }
        if (g < 32) eS[g >> 4][g & 15] = map[(long)(a0 + (g >> 4)*256)*VN + p0 + (g & 15)];
        XI_CHAIN(0);
        XI_CHAIN(1);
        __syncthreads();

        // ---- phase A region 2: stage x(p+1), corr gather into xiP(p) ----
        if (hasnext) STAGE(p0 + TP);
        CORR_ADD();
        __syncthreads();

        // ---- 16 gate steps (pure LDS/MFMA/VALU) ----
        STEP(0);  STEP(1);  STEP(2);  STEP(3);
        STEP(4);  STEP(5);  STEP(6);  STEP(7);
        STEP(8);  STEP(9);  STEP(10); STEP(11);
        STEP(12); STEP(13); STEP(14); STEP(15);
    }
    // ---- final write-back ----
    {
        int pp = VN - TP;
        for (int idx = g; idx < 2*TP*32; idx += 512) {
            int rs = idx >> 9, j = idx & 511, t = j >> 5, c4 = j & 31;
            *(float4*)&x[((long)(a0 + rs*256)*VN + pp + t)*HN + c4*4] =
                *(const float4*)&hOut[rs][t][c4*4];
        }
    }
}

extern "C" void kernel_launch(void* const* d_in, const int* in_sizes, int n_in,
                              void* d_out, int out_size, void* d_ws, size_t ws_size,
                              hipStream_t stream) {
    const float* adj   = (const float*)d_in[0];
    const void*  edges = d_in[1];
    const float* emb   = (const float*)d_in[2];
    const float* w1    = (const float*)d_in[3];
    const float* w2    = (const float*)d_in[4];
    const float* w3    = (const float*)d_in[5];
    const float* wih   = (const float*)d_in[6];
    const float* whh   = (const float*)d_in[7];
    const float* bih   = (const float*)d_in[8];
    const float* bhh   = (const float*)d_in[9];

    float* x = (float*)d_out;          // x lives in d_out; scan updates it in place

    char* p = (char*)d_ws;
    auto alloc = [&](size_t bytes) { char* r = p; p += (bytes + 255) & ~255UL; return r; };
    float* in3    = (float*)alloc((size_t)EN*G3*4);
    float* corr   = (float*)alloc((size_t)EN*G3*4);
    float* colsum = (float*)alloc((size_t)VN*HN*4);
    int*   nnz    = (int*)  alloc((size_t)VN*4);
    int*   map    = (int*)  alloc((size_t)NROWS*4);
    int*   uA     = (int*)  alloc((size_t)EN*4);
    int*   vA     = (int*)  alloc((size_t)EN*4);
    unsigned short* wsF = (unsigned short*)alloc((size_t)24*4*64*8*2);
    unsigned short* whF = (unsigned short*)alloc((size_t)24*4*64*8*2);
    unsigned short* wlF = (unsigned short*)alloc((size_t)24*4*64*8*2);
    unsigned short* wcF = (unsigned short*)alloc((size_t)3*8*12*64*8*2);

    k_edges<<<EN/256, 256, 0, stream>>>(edges, uA, vA);
    k_pack<<<(3*8*12*64*8 + 255)/256, 256, 0, stream>>>(w1, w2, w3, wih, whh,
        wsF, whF, wlF, wcF);
    k_fill<<<NROWS/256, 256, 0, stream>>>(map, -1, NROWS);
    k_map<<<EN/256, 256, 0, stream>>>(uA, vA, map);
    k_embed<<<NROWS/2, 256, 0, stream>>>(adj, emb, x);

    for (int l = 0; l < LN; l++) {
        k_colsum<<<VN, 512, 0, stream>>>(x, colsum, nnz);
        k_edgein<<<EN/4, 256, 0, stream>>>(x, uA, vA, colsum, nnz, in3);
        k_msgcorr<<<EN/16, 512, 0, stream>>>(in3, wcF + (long)l*8*12*64*8, wlF, corr);
        k_scanf<<<VN/2, 512, 0, stream>>>(x, wsF, whF, bih, bhh, corr, map);
    }
}

// Round 17
// 1847.731 us; speedup vs baseline: 1.4622x; 1.4622x over previous
//
#include <hip/hip_runtime.h>

#define VN 512
#define EN 32768
#define FN 8
#define HN 128
#define G3 384
#define LN 3
#define TP 16
#define NROWS (VN*VN)   // 262144
#define XIPAD 388       // 4*388 % 32 == 16 -> 2-way LDS aliasing (free)

typedef _Float16 f16x8 __attribute__((ext_vector_type(8)));
typedef float f32x4  __attribute__((ext_vector_type(4)));

__device__ __forceinline__ unsigned short f2h(float f) {
    _Float16 h = (_Float16)f;
    return __builtin_bit_cast(unsigned short, h);
}
__device__ __forceinline__ float h2f(unsigned short u) {
    return (float)__builtin_bit_cast(_Float16, u);
}
__device__ __forceinline__ float fexp2(float x) {
    float r; asm("v_exp_f32 %0, %1" : "=v"(r) : "v"(x)); return r;
}
__device__ __forceinline__ float frcp(float x) {
    float r; asm("v_rcp_f32 %0, %1" : "=v"(r) : "v"(x)); return r;
}
__device__ __forceinline__ float fsigmoid(float x) {
    return frcp(1.f + fexp2(x * -1.44269504089f));
}
__device__ __forceinline__ float ftanh(float x) {
    return 1.f - 2.f * frcp(1.f + fexp2(x * 2.88539008178f));
}

// ---------------- generic int fill ----------------
__global__ void k_fill(int* __restrict__ p, int val, int n) {
    int i = blockIdx.x * 256 + threadIdx.x;
    if (i < n) p[i] = val;
}

// ---------------- edge canonicalize (+ int64 detection) ----------------
__global__ void k_edges(const void* __restrict__ raw, int* __restrict__ uo, int* __restrict__ vo) {
    const int* r32 = (const int*)raw;
    const long long* r64 = (const long long*)raw;
    int acc = 0;
    #pragma unroll
    for (int i = 1; i < 128; i += 2) acc |= r32[i];
    bool is64 = (acc == 0);
    int e = blockIdx.x * 256 + threadIdx.x;
    if (e < EN) {
        int u, v;
        if (is64) { u = (int)r64[2*e]; v = (int)r64[2*e+1]; }
        else      { u = r32[2*e];      v = r32[2*e+1]; }
        uo[e] = u; vo[e] = v;
    }
}

// ---------------- pack weight B-fragments (single f16, MFMA lane layout) ----------------
// frag layout: [..ntile..][ktile][lane][elem]: k = kt*32 + (lane>>4)*8 + e ; col = nt*16 + (lane&15)
__global__ void k_pack(const float* __restrict__ w1, const float* __restrict__ w2,
                       const float* __restrict__ w3, const float* __restrict__ wih,
                       const float* __restrict__ whh,
                       unsigned short* __restrict__ wsF, unsigned short* __restrict__ whF,
                       unsigned short* __restrict__ wlF, unsigned short* __restrict__ wcF) {
    int t = blockIdx.x * 256 + threadIdx.x;
    if (t < 3*8*12*64*8) {        // wcat frags [l][nt0..7][kt0..11]
        int e = t & 7, lane = (t >> 3) & 63;
        int frag = t >> 9;
        int kt = frag % 12;
        int rem = frag / 12;
        int nt = rem & 7;
        int l  = rem >> 3;
        int k  = kt*32 + (lane >> 4)*8 + e;
        int gc = nt*16 + (lane & 15);
        const float* w = (k < 128) ? w1 : (k < 256 ? w2 : w3);
        wcF[t] = f2h(w[((long)l*128 + gc)*128 + (k & 127)]);
    }
    if (t < 24*4*64*8) {          // wsum / whh / wl frags [nt0..23][kt0..3]
        int e = t & 7, lane = (t >> 3) & 63, kt = (t >> 9) & 3, nt = t >> 11;
        int k  = kt*32 + (lane >> 4)*8 + e;
        int gc = nt*16 + (lane & 15);
        wsF[t] = f2h(wih[gc*256 + k] + wih[gc*256 + 128 + k]);
        whF[t] = f2h(whh[gc*HN + k]);
        wlF[t] = f2h(wih[gc*256 + k]);
    }
}

// ---------------- winner map ----------------
__global__ void k_map(const int* __restrict__ uA, const int* __restrict__ vA, int* __restrict__ map) {
    int e = blockIdx.x * 256 + threadIdx.x;
    if (e < EN) atomicMax(&map[uA[e]*VN + vA[e]], e);
}

// ---------------- embed ----------------
__global__ __launch_bounds__(256) void k_embed(const float* __restrict__ adj,
                                               const float* __restrict__ emb,
                                               float* __restrict__ x) {
    __shared__ float semb[HN][FN];
    __shared__ float sadj[2][FN];
    int tid = threadIdx.x;
    for (int i = tid; i < HN*FN; i += 256) semb[i/FN][i%FN] = emb[i];
    if (tid < 16) sadj[tid>>3][tid&7] = adj[(long)blockIdx.x*16 + tid];
    __syncthreads();
    int p = tid >> 7;
    int h = tid & 127;
    float acc = 0.f;
    #pragma unroll
    for (int f = 0; f < FN; f++) acc += sadj[p][f]*semb[h][f];
    long row = (long)blockIdx.x*2 + p;
    x[row*HN + h] = acc;
}

// ---------------- colsum + nnz ----------------
__global__ __launch_bounds__(512) void k_colsum(const float* __restrict__ x,
                                                float* __restrict__ colsum, int* __restrict__ nnz) {
    int b = blockIdx.x;
    int tid = threadIdx.x;
    int h = tid & 127, q = tid >> 7;
    float s = 0.f; int c = 0;
    for (int a = q*128; a < q*128 + 128; a++) {
        float v = x[((long)a*VN + b)*HN + h];
        s += v; c += (v != 0.f) ? 1 : 0;
    }
    __shared__ float ss[4][128];
    __shared__ int sc[8];
    ss[q][h] = s;
    #pragma unroll
    for (int off = 32; off; off >>= 1) c += __shfl_down(c, off);
    if ((tid & 63) == 0) sc[tid>>6] = c;
    __syncthreads();
    if (tid < 128) colsum[b*HN + tid] = ss[0][tid]+ss[1][tid]+ss[2][tid]+ss[3][tid];
    if (tid == 0) { int t = 0; for (int i = 0; i < 8; i++) t += sc[i]; nnz[b] = t; }
}

// ---------------- edge inputs ----------------
__global__ __launch_bounds__(256) void k_edgein(const float* __restrict__ x,
    const int* __restrict__ uA, const int* __restrict__ vA,
    const float* __restrict__ colsum, const int* __restrict__ nnz, float* __restrict__ in3) {
    int w = threadIdx.x >> 6;
    int lane = threadIdx.x & 63;
    int e = blockIdx.x*4 + w;
    int u = uA[e], v = vA[e];
    const float* xuv = x + ((long)u*VN + v)*HN;
    const float* xvu = x + ((long)v*VN + u)*HN;
    float xu0 = xuv[lane], xu1 = xuv[lane+64];
    float xv0 = xvu[lane], xv1 = xvu[lane+64];
    int cnt_vu = __popcll(__ballot(xv0 != 0.f)) + __popcll(__ballot(xv1 != 0.f));
    int cnt_uv = __popcll(__ballot(xu0 != 0.f)) + __popcll(__ballot(xu1 != 0.f));
    float nin  = (float)(nnz[u] - cnt_vu) * (1.f/128.f); if (nin  == 0.f) nin  = 1.f;
    float nout = (float)(nnz[v] - cnt_uv) * (1.f/128.f); if (nout == 0.f) nout = 1.f;
    float* o = in3 + (long)e*G3;
    o[lane]        = xu0;  o[lane+64]      = xu1;
    o[128+lane]    = (colsum[u*HN+lane]    - xv0)/nin;
    o[128+lane+64] = (colsum[u*HN+lane+64] - xv1)/nin;
    o[256+lane]    = (colsum[v*HN+lane]    - xu0)/nout;
    o[256+lane+64] = (colsum[v*HN+lane+64] - xu1)/nout;
}

#define MF16(A,B,C) __builtin_amdgcn_mfma_f32_16x16x32_f16((A),(B),(C),0,0,0)
#define Z4 ((f32x4){0.f,0.f,0.f,0.f})

// ---------------- fused msg+corr (f16 MFMA) ----------------
__global__ __launch_bounds__(512) void k_msgcorr(
    const float* __restrict__ in3,
    const unsigned short* __restrict__ wcF, const unsigned short* __restrict__ wlF,
    float* __restrict__ corr) {
    const int g = threadIdx.x;
    const int wv = g >> 6;
    const int lane = g & 63;
    const int r16 = lane & 15;
    const int kgrp = lane >> 4;
    const long m0 = (long)blockIdx.x * 16;

    __shared__ unsigned short Dh[16][136];
    __shared__ unsigned short Dl[16][136];

    f32x4 pacc[2];
    pacc[0] = Z4; pacc[1] = Z4;
    #pragma unroll
    for (int kt = 0; kt < 12; kt++) {
        const float* xs = &in3[(m0 + r16)*G3 + kt*32 + kgrp*8];
        float4 v0 = *(const float4*)xs;
        float4 v1 = *(const float4*)(xs + 4);
        float vv[8] = {v0.x,v0.y,v0.z,v0.w,v1.x,v1.y,v1.z,v1.w};
        f16x8 H, L;
        #pragma unroll
        for (int j = 0; j < 8; j++) {
            _Float16 h = (_Float16)vv[j];
            H[j] = h;
            L[j] = (_Float16)(vv[j] - (float)h);
        }
        f16x8 bF = *(const f16x8*)&wcF[(((long)wv*12 + kt)*64 + lane)*8];
        const int p = kt & 1;
        pacc[p] = MF16(H, bF, pacc[p]);
        pacc[p] = MF16(L, bF, pacc[p]);
    }
    const int c = wv*16 + r16;
    #pragma unroll
    for (int r = 0; r < 4; r++) {
        int m = kgrp*4 + r;
        float mv = fmaxf(pacc[0][r] + pacc[1][r], 0.f) - in3[(m0 + m)*G3 + c];
        unsigned short hi = f2h(mv);
        Dh[m][c] = hi;
        Dl[m][c] = f2h(mv - h2f(hi));
    }
    __syncthreads();

    f32x4 cacc[3];
    cacc[0] = cacc[1] = cacc[2] = Z4;
    #pragma unroll
    for (int kt = 0; kt < 4; kt++) {
        f16x8 ah = *(const f16x8*)&Dh[r16][kt*32 + kgrp*8];
        f16x8 al = *(const f16x8*)&Dl[r16][kt*32 + kgrp*8];
        #pragma unroll
        for (int j = 0; j < 3; j++) {
            f16x8 bF = *(const f16x8*)&wlF[(((long)(wv*3 + j)*4 + kt)*64 + lane)*8];
            cacc[j] = MF16(ah, bF, cacc[j]);
            cacc[j] = MF16(al, bF, cacc[j]);
        }
    }
    #pragma unroll
    for (int j = 0; j < 3; j++) {
        int n = (wv*3 + j)*16 + r16;
        #pragma unroll
        for (int r = 0; r < 4; r++)
            corr[(m0 + kgrp*4 + r)*G3 + n] = cacc[j][r];
    }
}

// ================= fused xi(f16 MFMA, phase-A) + GRU scan (v15: 1 chain/block, lean) =================
// 512 blocks x 512 threads (8 waves); block owns ONE chain a0.
// Register budget: wH resident 48 + hA 16 + 3 gacc (12 accum) + misc -> target
// unified total <=128 so the HW bucket gives 4 waves/SIMD = 2 blocks/CU
// (grid 512 = 2/CU available, unlike the 256-block 2-chain layout).
// NO launch_bounds min-waves clamp (r12/r16: it forces arch=64 and spills).
// Single chain => gh row 0 sits in lanes 0-15 reg 0: no swizzle/bpermute at all.
// LDS ~37.5 KB. Steps pure LDS/MFMA/VALU, one barrier each.

// stage x rows [ROWBASE, ROWBASE+16) into xS (f16 hi, 4-bit XOR swizzle)
#define STAGE(ROWBASE) do { if (g < 256) { \
    int row_ = g >> 4, cg_ = g & 15; \
    const float* xs_ = &x[((long)a0*VN + (ROWBASE) + row_)*HN + cg_*8]; \
    float4 v0_ = *(const float4*)xs_; \
    float4 v1_ = *(const float4*)(xs_ + 4); \
    f16x8 H_; \
    H_[0] = (_Float16)v0_.x; H_[1] = (_Float16)v0_.y; \
    H_[2] = (_Float16)v0_.z; H_[3] = (_Float16)v0_.w; \
    H_[4] = (_Float16)v1_.x; H_[5] = (_Float16)v1_.y; \
    H_[6] = (_Float16)v1_.z; H_[7] = (_Float16)v1_.w; \
    int slot_ = cg_ ^ row_; \
    *(f16x8*)&xSh[row_][slot_*8] = H_; \
} } while(0)

#define XB(GI,KT) (*(const f16x8*)&wsF[(((long)((GI)*8 + wv)*4 + (KT))*64 + lane)*8])
#define XA(KT)    (*(const f16x8*)&xSh[r16][((((KT)*4 + kgrp) ^ r16)*8)])

// xi for the chain: 4 A-frags, 3 accumulators, 12 MFMA, store w/ bias
#define XI_CHAIN() do { \
    f16x8 xA0_ = XA(0), xA1_ = XA(1), xA2_ = XA(2), xA3_ = XA(3); \
    f32x4 aR_ = Z4, aZ_ = Z4, aN_ = Z4; \
    aR_ = MF16(xA0_, XB(0,0), aR_); \
    aZ_ = MF16(xA0_, XB(1,0), aZ_); \
    aN_ = MF16(xA0_, XB(2,0), aN_); \
    aR_ = MF16(xA1_, XB(0,1), aR_); \
    aZ_ = MF16(xA1_, XB(1,1), aZ_); \
    aN_ = MF16(xA1_, XB(2,1), aN_); \
    aR_ = MF16(xA2_, XB(0,2), aR_); \
    aZ_ = MF16(xA2_, XB(1,2), aZ_); \
    aN_ = MF16(xA2_, XB(2,2), aN_); \
    aR_ = MF16(xA3_, XB(0,3), aR_); \
    aZ_ = MF16(xA3_, XB(1,3), aZ_); \
    aN_ = MF16(xA3_, XB(2,3), aN_); \
    _Pragma("unroll") \
    for (int r_ = 0; r_ < 4; ++r_) { \
        xiP[kgrp*4 + r_][c]        = aR_[r_] + biR; \
        xiP[kgrp*4 + r_][HN + c]   = aZ_[r_] + biZ; \
        xiP[kgrp*4 + r_][2*HN + c] = aN_[r_] + biN; \
    } \
} while(0)

#define CORR_ADD() do { if (g < G3) { \
    for (int t_ = 0; t_ < TP; ++t_) { \
        int e_ = eS[t_]; \
        if (e_ >= 0) xiP[t_][g] += corr[(long)e_*G3 + g]; \
    } } } while(0)

#define STEP(T) do { \
    f16x8 hA0_ = *(const f16x8*)&hSh[cur][0*32 + kgrp*8]; \
    f16x8 hA1_ = *(const f16x8*)&hSh[cur][1*32 + kgrp*8]; \
    f16x8 hA2_ = *(const f16x8*)&hSh[cur][2*32 + kgrp*8]; \
    f16x8 hA3_ = *(const f16x8*)&hSh[cur][3*32 + kgrp*8]; \
    f32x4 gr_ = Z4, gz_ = Z4, gn_ = Z4; \
    __builtin_amdgcn_s_setprio(1); \
    gr_ = MF16(hA0_, wH[0], gr_); \
    gz_ = MF16(hA0_, wH[4], gz_); \
    gn_ = MF16(hA0_, wH[8], gn_); \
    gr_ = MF16(hA1_, wH[1], gr_); \
    gz_ = MF16(hA1_, wH[5], gz_); \
    gn_ = MF16(hA1_, wH[9], gn_); \
    gr_ = MF16(hA2_, wH[2], gr_); \
    gz_ = MF16(hA2_, wH[6], gz_); \
    gn_ = MF16(hA2_, wH[10], gn_); \
    gr_ = MF16(hA3_, wH[3], gr_); \
    gz_ = MF16(hA3_, wH[7], gz_); \
    gn_ = MF16(hA3_, wH[11], gn_); \
    __builtin_amdgcn_s_setprio(0); \
    if (lane < 16) { \
        float xr_ = xiP[T][c]; \
        float xz_ = xiP[T][HN + c]; \
        float xn_ = xiP[T][2*HN + c]; \
        float r_ = fsigmoid(xr_ + gr_[0] + br); \
        float z_ = fsigmoid(xz_ + gz_[0] + bz); \
        float n_ = ftanh(xn_ + r_*(gn_[0] + bn)); \
        float h_ = (1.f - z_)*n_ + z_*hprev; \
        hprev = h_; \
        hOut[T][c] = h_; \
        hSh[cur ^ 1][c] = f2h(h_); \
    } \
    cur ^= 1; \
    __syncthreads(); \
} while(0)

__global__ __launch_bounds__(512) void k_scanf(
    float* __restrict__ x,
    const unsigned short* __restrict__ wsF, const unsigned short* __restrict__ whF,
    const float* __restrict__ bih, const float* __restrict__ bhh,
    const float* __restrict__ corr, const int* __restrict__ map) {
    const int g = threadIdx.x;
    const int a0 = blockIdx.x;
    const int wv = g >> 6;
    const int lane = g & 63;
    const int r16 = lane & 15;
    const int kgrp = lane >> 4;

    __shared__ float xiP[TP][XIPAD];                // 24.8 KB
    __shared__ unsigned short xSh[TP][HN];          // 4 KB (row, swz col) -- f16 hi only
    __shared__ unsigned short hSh[2][HN];           // [parity][col] 512 B -- f16 single
    __shared__ float hOut[TP][HN];                  // 8 KB
    __shared__ int eS[TP];                          // total ~37.4 KB

    // resident whh B-frags only (48 VGPRs); wsF streamed in phase A
    f16x8 wH[12];
    #pragma unroll
    for (int gi = 0; gi < 3; gi++)
        #pragma unroll
        for (int kt = 0; kt < 4; kt++) {
            long bidx = (((long)(gi*8 + wv)*4 + kt)*64 + lane)*8;
            wH[gi*4+kt] = *(const f16x8*)&whF[bidx];
        }

    const int c = wv*16 + r16;
    const float br = bhh[c],  bz = bhh[HN + c],  bn = bhh[2*HN + c];
    const float biR = bih[c], biZ = bih[HN + c], biN = bih[2*HN + c];
    float hprev = 0.f;                  // lanes<16 hold the chain state

    if (g < HN) hSh[0][g] = 0;
    int cur = 0;

    // ---- prologue: stage panel 0 ----
    STAGE(0);
    __syncthreads();

    for (int p0 = 0; p0 < VN; p0 += TP) {
        const bool hasnext = (p0 + TP) < VN;

        // ---- phase A region 1: writeback(p-1), eS(p), xi(p) from xS (B-frags from L2) ----
        if (p0 > 0) {
            int pp = p0 - TP;
            int t = g >> 5, c4 = g & 31;
            *(float4*)&x[((long)a0*VN + pp + t)*HN + c4*4] = *(const float4*)&hOut[t][c4*4];
        }
        if (g < TP) eS[g] = map[(long)a0*VN + p0 + g];
        XI_CHAIN();
        __syncthreads();

        // ---- phase A region 2: stage x(p+1), corr gather into xiP(p) ----
        if (hasnext) STAGE(p0 + TP);
        CORR_ADD();
        __syncthreads();

        // ---- 16 gate steps (pure LDS/MFMA/VALU) ----
        STEP(0);  STEP(1);  STEP(2);  STEP(3);
        STEP(4);  STEP(5);  STEP(6);  STEP(7);
        STEP(8);  STEP(9);  STEP(10); STEP(11);
        STEP(12); STEP(13); STEP(14); STEP(15);
    }
    // ---- final write-back ----
    {
        int pp = VN - TP;
        int t = g >> 5, c4 = g & 31;
        *(float4*)&x[((long)a0*VN + pp + t)*HN + c4*4] = *(const float4*)&hOut[t][c4*4];
    }
}

extern "C" void kernel_launch(void* const* d_in, const int* in_sizes, int n_in,
                              void* d_out, int out_size, void* d_ws, size_t ws_size,
                              hipStream_t stream) {
    const float* adj   = (const float*)d_in[0];
    const void*  edges = d_in[1];
    const float* emb   = (const float*)d_in[2];
    const float* w1    = (const float*)d_in[3];
    const float* w2    = (const float*)d_in[4];
    const float* w3    = (const float*)d_in[5];
    const float* wih   = (const float*)d_in[6];
    const float* whh   = (const float*)d_in[7];
    const float* bih   = (const float*)d_in[8];
    const float* bhh   = (const float*)d_in[9];

    float* x = (float*)d_out;          // x lives in d_out; scan updates it in place

    char* p = (char*)d_ws;
    auto alloc = [&](size_t bytes) { char* r = p; p += (bytes + 255) & ~255UL; return r; };
    float* in3    = (float*)alloc((size_t)EN*G3*4);
    float* corr   = (float*)alloc((size_t)EN*G3*4);
    float* colsum = (float*)alloc((size_t)VN*HN*4);
    int*   nnz    = (int*)  alloc((size_t)VN*4);
    int*   map    = (int*)  alloc((size_t)NROWS*4);
    int*   uA     = (int*)  alloc((size_t)EN*4);
    int*   vA     = (int*)  alloc((size_t)EN*4);
    unsigned short* wsF = (unsigned short*)alloc((size_t)24*4*64*8*2);
    unsigned short* whF = (unsigned short*)alloc((size_t)24*4*64*8*2);
    unsigned short* wlF = (unsigned short*)alloc((size_t)24*4*64*8*2);
    unsigned short* wcF = (unsigned short*)alloc((size_t)3*8*12*64*8*2);

    k_edges<<<EN/256, 256, 0, stream>>>(edges, uA, vA);
    k_pack<<<(3*8*12*64*8 + 255)/256, 256, 0, stream>>>(w1, w2, w3, wih, whh,
        wsF, whF, wlF, wcF);
    k_fill<<<NROWS/256, 256, 0, stream>>>(map, -1, NROWS);
    k_map<<<EN/256, 256, 0, stream>>>(uA, vA, map);
    k_embed<<<NROWS/2, 256, 0, stream>>>(adj, emb, x);

    for (int l = 0; l < LN; l++) {
        k_colsum<<<VN, 512, 0, stream>>>(x, colsum, nnz);
        k_edgein<<<EN/4, 256, 0, stream>>>(x, uA, vA, colsum, nnz, in3);
        k_msgcorr<<<EN/16, 512, 0, stream>>>(in3, wcF + (long)l*8*12*64*8, wlF, corr);
        k_scanf<<<VN, 512, 0, stream>>>(x, wsF, whF, bih, bhh, corr, map);
    }
}

// Round 18
// 1413.221 us; speedup vs baseline: 1.9117x; 1.3075x over previous
//
#include <hip/hip_runtime.h>

#define VN 512
#define EN 32768
#define FN 8
#define HN 128
#define G3 384
#define LN 3
#define TP 16
#define NROWS (VN*VN)   // 262144
#define XIPAD 388       // 4*388 % 32 == 16 -> 2-way LDS aliasing (free)

typedef _Float16 f16x8 __attribute__((ext_vector_type(8)));
typedef float f32x4  __attribute__((ext_vector_type(4)));

__device__ __forceinline__ unsigned short f2h(float f) {
    _Float16 h = (_Float16)f;
    return __builtin_bit_cast(unsigned short, h);
}
__device__ __forceinline__ float h2f(unsigned short u) {
    return (float)__builtin_bit_cast(_Float16, u);
}
__device__ __forceinline__ float fexp2(float x) {
    float r; asm("v_exp_f32 %0, %1" : "=v"(r) : "v"(x)); return r;
}
__device__ __forceinline__ float frcp(float x) {
    float r; asm("v_rcp_f32 %0, %1" : "=v"(r) : "v"(x)); return r;
}
__device__ __forceinline__ float fsigmoid(float x) {
    return frcp(1.f + fexp2(x * -1.44269504089f));
}
__device__ __forceinline__ float ftanh(float x) {
    return 1.f - 2.f * frcp(1.f + fexp2(x * 2.88539008178f));
}

// ---------------- generic int fill ----------------
__global__ void k_fill(int* __restrict__ p, int val, int n) {
    int i = blockIdx.x * 256 + threadIdx.x;
    if (i < n) p[i] = val;
}

// ---------------- edge canonicalize (+ int64 detection) ----------------
__global__ void k_edges(const void* __restrict__ raw, int* __restrict__ uo, int* __restrict__ vo) {
    const int* r32 = (const int*)raw;
    const long long* r64 = (const long long*)raw;
    int acc = 0;
    #pragma unroll
    for (int i = 1; i < 128; i += 2) acc |= r32[i];
    bool is64 = (acc == 0);
    int e = blockIdx.x * 256 + threadIdx.x;
    if (e < EN) {
        int u, v;
        if (is64) { u = (int)r64[2*e]; v = (int)r64[2*e+1]; }
        else      { u = r32[2*e];      v = r32[2*e+1]; }
        uo[e] = u; vo[e] = v;
    }
}

// ---------------- pack weight B-fragments (single f16, MFMA lane layout) ----------------
// frag layout: [..ntile..][ktile][lane][elem]: k = kt*32 + (lane>>4)*8 + e ; col = nt*16 + (lane&15)
__global__ void k_pack(const float* __restrict__ w1, const float* __restrict__ w2,
                       const float* __restrict__ w3, const float* __restrict__ wih,
                       const float* __restrict__ whh,
                       unsigned short* __restrict__ wsF, unsigned short* __restrict__ whF,
                       unsigned short* __restrict__ wlF, unsigned short* __restrict__ wcF) {
    int t = blockIdx.x * 256 + threadIdx.x;
    if (t < 3*8*12*64*8) {        // wcat frags [l][nt0..7][kt0..11]
        int e = t & 7, lane = (t >> 3) & 63;
        int frag = t >> 9;
        int kt = frag % 12;
        int rem = frag / 12;
        int nt = rem & 7;
        int l  = rem >> 3;
        int k  = kt*32 + (lane >> 4)*8 + e;
        int gc = nt*16 + (lane & 15);
        const float* w = (k < 128) ? w1 : (k < 256 ? w2 : w3);
        wcF[t] = f2h(w[((long)l*128 + gc)*128 + (k & 127)]);
    }
    if (t < 24*4*64*8) {          // wsum / whh / wl frags [nt0..23][kt0..3]
        int e = t & 7, lane = (t >> 3) & 63, kt = (t >> 9) & 3, nt = t >> 11;
        int k  = kt*32 + (lane >> 4)*8 + e;
        int gc = nt*16 + (lane & 15);
        wsF[t] = f2h(wih[gc*256 + k] + wih[gc*256 + 128 + k]);
        whF[t] = f2h(whh[gc*HN + k]);
        wlF[t] = f2h(wih[gc*256 + k]);
    }
}

// ---------------- winner map ----------------
__global__ void k_map(const int* __restrict__ uA, const int* __restrict__ vA, int* __restrict__ map) {
    int e = blockIdx.x * 256 + threadIdx.x;
    if (e < EN) atomicMax(&map[uA[e]*VN + vA[e]], e);
}

// ---------------- embed ----------------
__global__ __launch_bounds__(256) void k_embed(const float* __restrict__ adj,
                                               const float* __restrict__ emb,
                                               float* __restrict__ x) {
    __shared__ float semb[HN][FN];
    __shared__ float sadj[2][FN];
    int tid = threadIdx.x;
    for (int i = tid; i < HN*FN; i += 256) semb[i/FN][i%FN] = emb[i];
    if (tid < 16) sadj[tid>>3][tid&7] = adj[(long)blockIdx.x*16 + tid];
    __syncthreads();
    int p = tid >> 7;
    int h = tid & 127;
    float acc = 0.f;
    #pragma unroll
    for (int f = 0; f < FN; f++) acc += sadj[p][f]*semb[h][f];
    long row = (long)blockIdx.x*2 + p;
    x[row*HN + h] = acc;
}

// ---------------- colsum + nnz ----------------
__global__ __launch_bounds__(512) void k_colsum(const float* __restrict__ x,
                                                float* __restrict__ colsum, int* __restrict__ nnz) {
    int b = blockIdx.x;
    int tid = threadIdx.x;
    int h = tid & 127, q = tid >> 7;
    float s = 0.f; int c = 0;
    for (int a = q*128; a < q*128 + 128; a++) {
        float v = x[((long)a*VN + b)*HN + h];
        s += v; c += (v != 0.f) ? 1 : 0;
    }
    __shared__ float ss[4][128];
    __shared__ int sc[8];
    ss[q][h] = s;
    #pragma unroll
    for (int off = 32; off; off >>= 1) c += __shfl_down(c, off);
    if ((tid & 63) == 0) sc[tid>>6] = c;
    __syncthreads();
    if (tid < 128) colsum[b*HN + tid] = ss[0][tid]+ss[1][tid]+ss[2][tid]+ss[3][tid];
    if (tid == 0) { int t = 0; for (int i = 0; i < 8; i++) t += sc[i]; nnz[b] = t; }
}

// ---------------- edge inputs ----------------
__global__ __launch_bounds__(256) void k_edgein(const float* __restrict__ x,
    const int* __restrict__ uA, const int* __restrict__ vA,
    const float* __restrict__ colsum, const int* __restrict__ nnz, float* __restrict__ in3) {
    int w = threadIdx.x >> 6;
    int lane = threadIdx.x & 63;
    int e = blockIdx.x*4 + w;
    int u = uA[e], v = vA[e];
    const float* xuv = x + ((long)u*VN + v)*HN;
    const float* xvu = x + ((long)v*VN + u)*HN;
    float xu0 = xuv[lane], xu1 = xuv[lane+64];
    float xv0 = xvu[lane], xv1 = xvu[lane+64];
    int cnt_vu = __popcll(__ballot(xv0 != 0.f)) + __popcll(__ballot(xv1 != 0.f));
    int cnt_uv = __popcll(__ballot(xu0 != 0.f)) + __popcll(__ballot(xu1 != 0.f));
    float nin  = (float)(nnz[u] - cnt_vu) * (1.f/128.f); if (nin  == 0.f) nin  = 1.f;
    float nout = (float)(nnz[v] - cnt_uv) * (1.f/128.f); if (nout == 0.f) nout = 1.f;
    float* o = in3 + (long)e*G3;
    o[lane]        = xu0;  o[lane+64]      = xu1;
    o[128+lane]    = (colsum[u*HN+lane]    - xv0)/nin;
    o[128+lane+64] = (colsum[u*HN+lane+64] - xv1)/nin;
    o[256+lane]    = (colsum[v*HN+lane]    - xu0)/nout;
    o[256+lane+64] = (colsum[v*HN+lane+64] - xu1)/nout;
}

#define MF16(A,B,C) __builtin_amdgcn_mfma_f32_16x16x32_f16((A),(B),(C),0,0,0)
#define Z4 ((f32x4){0.f,0.f,0.f,0.f})

// ---------------- fused msg+corr (f16 MFMA) ----------------
__global__ __launch_bounds__(512) void k_msgcorr(
    const float* __restrict__ in3,
    const unsigned short* __restrict__ wcF, const unsigned short* __restrict__ wlF,
    float* __restrict__ corr) {
    const int g = threadIdx.x;
    const int wv = g >> 6;
    const int lane = g & 63;
    const int r16 = lane & 15;
    const int kgrp = lane >> 4;
    const long m0 = (long)blockIdx.x * 16;

    __shared__ unsigned short Dh[16][136];
    __shared__ unsigned short Dl[16][136];

    f32x4 pacc[2];
    pacc[0] = Z4; pacc[1] = Z4;
    #pragma unroll
    for (int kt = 0; kt < 12; kt++) {
        const float* xs = &in3[(m0 + r16)*G3 + kt*32 + kgrp*8];
        float4 v0 = *(const float4*)xs;
        float4 v1 = *(const float4*)(xs + 4);
        float vv[8] = {v0.x,v0.y,v0.z,v0.w,v1.x,v1.y,v1.z,v1.w};
        f16x8 H, L;
        #pragma unroll
        for (int j = 0; j < 8; j++) {
            _Float16 h = (_Float16)vv[j];
            H[j] = h;
            L[j] = (_Float16)(vv[j] - (float)h);
        }
        f16x8 bF = *(const f16x8*)&wcF[(((long)wv*12 + kt)*64 + lane)*8];
        const int p = kt & 1;
        pacc[p] = MF16(H, bF, pacc[p]);
        pacc[p] = MF16(L, bF, pacc[p]);
    }
    const int c = wv*16 + r16;
    #pragma unroll
    for (int r = 0; r < 4; r++) {
        int m = kgrp*4 + r;
        float mv = fmaxf(pacc[0][r] + pacc[1][r], 0.f) - in3[(m0 + m)*G3 + c];
        unsigned short hi = f2h(mv);
        Dh[m][c] = hi;
        Dl[m][c] = f2h(mv - h2f(hi));
    }
    __syncthreads();

    f32x4 cacc[3];
    cacc[0] = cacc[1] = cacc[2] = Z4;
    #pragma unroll
    for (int kt = 0; kt < 4; kt++) {
        f16x8 ah = *(const f16x8*)&Dh[r16][kt*32 + kgrp*8];
        f16x8 al = *(const f16x8*)&Dl[r16][kt*32 + kgrp*8];
        #pragma unroll
        for (int j = 0; j < 3; j++) {
            f16x8 bF = *(const f16x8*)&wlF[(((long)(wv*3 + j)*4 + kt)*64 + lane)*8];
            cacc[j] = MF16(ah, bF, cacc[j]);
            cacc[j] = MF16(al, bF, cacc[j]);
        }
    }
    #pragma unroll
    for (int j = 0; j < 3; j++) {
        int n = (wv*3 + j)*16 + r16;
        #pragma unroll
        for (int r = 0; r < 4; r++)
            corr[(m0 + kgrp*4 + r)*G3 + n] = cacc[j][r];
    }
}

// ================= fused xi(f16 MFMA, phase-A) + GRU scan (r15 configuration) =================
// 256 blocks x 512 threads (8 waves); block owns chains {a0, a0+256}.
// Best measured config (r15: scanf 350us): h single-f16 (12 gh MFMA/wave/step),
// ds_swizzle xor-16 cross-chain move (conflict-free permutation), phase-A xi
// with wsF B-frags streamed from L2, wH-only resident (48 VGPRs), no clamp.
// Steps pure LDS/MFMA/VALU, one barrier each. LDS ~74.9 KB.

// stage x rows [ROWBASE, ROWBASE+16) of both chains into xS (f16 hi, 4-bit XOR swizzle)
#define STAGE(ROWBASE) do { \
    int rs_ = g >> 8, row_ = (g >> 4) & 15, cg_ = g & 15; \
    const float* xs_ = &x[((long)(a0 + rs_*256)*VN + (ROWBASE) + row_)*HN + cg_*8]; \
    float4 v0_ = *(const float4*)xs_; \
    float4 v1_ = *(const float4*)(xs_ + 4); \
    f16x8 H_; \
    H_[0] = (_Float16)v0_.x; H_[1] = (_Float16)v0_.y; \
    H_[2] = (_Float16)v0_.z; H_[3] = (_Float16)v0_.w; \
    H_[4] = (_Float16)v1_.x; H_[5] = (_Float16)v1_.y; \
    H_[6] = (_Float16)v1_.z; H_[7] = (_Float16)v1_.w; \
    int slot_ = cg_ ^ row_; \
    *(f16x8*)&xSh[rs_][row_][slot_*8] = H_; \
} while(0)

// xi item pair (both chains share one B-frag load from L2)
#define XI_PAIR(GI, KT) do { \
    f16x8 bF_ = *(const f16x8*)&wsF[(((long)((GI)*8 + wv)*4 + (KT))*64 + lane)*8]; \
    int slot_ = ((KT)*4 + kgrp) ^ r16; \
    f16x8 A0_ = *(const f16x8*)&xSh[0][r16][slot_*8]; \
    f16x8 A1_ = *(const f16x8*)&xSh[1][r16][slot_*8]; \
    xacc0##GI = MF16(A0_, bF_, xacc0##GI); \
    xacc1##GI = MF16(A1_, bF_, xacc1##GI); \
} while(0)

#define XI_STORE() do { \
    _Pragma("unroll") \
    for (int r_ = 0; r_ < 4; ++r_) { \
        xiP[0][kgrp*4 + r_][c]        = xacc00[r_] + biR; \
        xiP[0][kgrp*4 + r_][HN + c]   = xacc01[r_] + biZ; \
        xiP[0][kgrp*4 + r_][2*HN + c] = xacc02[r_] + biN; \
        xiP[1][kgrp*4 + r_][c]        = xacc10[r_] + biR; \
        xiP[1][kgrp*4 + r_][HN + c]   = xacc11[r_] + biZ; \
        xiP[1][kgrp*4 + r_][2*HN + c] = xacc12[r_] + biN; \
    } \
} while(0)

#define CORR_ADD() do { if (g < G3) { \
    for (int rs_ = 0; rs_ < 2; ++rs_) \
        for (int t_ = 0; t_ < TP; ++t_) { \
            int e_ = eS[rs_][t_]; \
            if (e_ >= 0) xiP[rs_][t_][g] += corr[(long)e_*G3 + g]; \
        } } } while(0)

#define STEP(T) do { \
    const int arow_ = r16 & 1; \
    f16x8 hA0_ = *(const f16x8*)&hSh[cur][arow_][0*32 + kgrp*8]; \
    f16x8 hA1_ = *(const f16x8*)&hSh[cur][arow_][1*32 + kgrp*8]; \
    f16x8 hA2_ = *(const f16x8*)&hSh[cur][arow_][2*32 + kgrp*8]; \
    f16x8 hA3_ = *(const f16x8*)&hSh[cur][arow_][3*32 + kgrp*8]; \
    f32x4 gr0_ = Z4, gr1_ = Z4, gz0_ = Z4, gz1_ = Z4, gn0_ = Z4, gn1_ = Z4; \
    __builtin_amdgcn_s_setprio(1); \
    gr0_ = MF16(hA0_, wH[0], gr0_); \
    gr1_ = MF16(hA1_, wH[1], gr1_); \
    gr0_ = MF16(hA2_, wH[2], gr0_); \
    gr1_ = MF16(hA3_, wH[3], gr1_); \
    gz0_ = MF16(hA0_, wH[4], gz0_); \
    gz1_ = MF16(hA1_, wH[5], gz1_); \
    gz0_ = MF16(hA2_, wH[6], gz0_); \
    gz1_ = MF16(hA3_, wH[7], gz1_); \
    gn0_ = MF16(hA0_, wH[8], gn0_); \
    gn1_ = MF16(hA1_, wH[9], gn1_); \
    gn0_ = MF16(hA2_, wH[10], gn0_); \
    gn1_ = MF16(hA3_, wH[11], gn1_); \
    __builtin_amdgcn_s_setprio(0); \
    float sR_ = gr0_[0] + gr1_[0], tR_ = gr0_[1] + gr1_[1]; \
    float sZ_ = gz0_[0] + gz1_[0], tZ_ = gz0_[1] + gz1_[1]; \
    float sN_ = gn0_[0] + gn1_[0], tN_ = gn0_[1] + gn1_[1]; \
    float mR_ = __int_as_float(__builtin_amdgcn_ds_swizzle(__float_as_int(tR_), 0x401F)); \
    float mZ_ = __int_as_float(__builtin_amdgcn_ds_swizzle(__float_as_int(tZ_), 0x401F)); \
    float mN_ = __int_as_float(__builtin_amdgcn_ds_swizzle(__float_as_int(tN_), 0x401F)); \
    float vR_ = (lane < 16) ? sR_ : mR_; \
    float vZ_ = (lane < 16) ? sZ_ : mZ_; \
    float vN_ = (lane < 16) ? sN_ : mN_; \
    if (lane < 32) { \
        int rs_ = lane >> 4; \
        float xr_ = xiP[rs_][T][c]; \
        float xz_ = xiP[rs_][T][HN + c]; \
        float xn_ = xiP[rs_][T][2*HN + c]; \
        float r_ = fsigmoid(xr_ + vR_ + br); \
        float z_ = fsigmoid(xz_ + vZ_ + bz); \
        float n_ = ftanh(xn_ + r_*(vN_ + bn)); \
        float h_ = (1.f - z_)*n_ + z_*hprev; \
        hprev = h_; \
        hOut[rs_][T][c] = h_; \
        hSh[cur ^ 1][rs_][c] = f2h(h_); \
    } \
    cur ^= 1; \
    __syncthreads(); \
} while(0)

__global__ __launch_bounds__(512) void k_scanf(
    float* __restrict__ x,
    const unsigned short* __restrict__ wsF, const unsigned short* __restrict__ whF,
    const float* __restrict__ bih, const float* __restrict__ bhh,
    const float* __restrict__ corr, const int* __restrict__ map) {
    const int g = threadIdx.x;
    const int a0 = blockIdx.x;
    const int wv = g >> 6;
    const int lane = g & 63;
    const int r16 = lane & 15;
    const int kgrp = lane >> 4;

    __shared__ float xiP[2][TP][XIPAD];             // 49.7 KB [chain][t][col3]
    __shared__ unsigned short xSh[2][TP][HN];       // 8 KB (chain, row, swz col) -- hi only
    __shared__ unsigned short hSh[2][2][HN];        // [parity][chain][col] 1 KB -- f16 single
    __shared__ float hOut[2][TP][HN];               // 16 KB
    __shared__ int eS[2][TP];                       // total ~74.9 KB

    // resident whh B-frags only (48 VGPRs); wsF streamed in phase A
    f16x8 wH[12];
    #pragma unroll
    for (int gi = 0; gi < 3; gi++)
        #pragma unroll
        for (int kt = 0; kt < 4; kt++) {
            long bidx = (((long)(gi*8 + wv)*4 + kt)*64 + lane)*8;
            wH[gi*4+kt] = *(const f16x8*)&whF[bidx];
        }

    const int c = wv*16 + r16;
    const float br = bhh[c],  bz = bhh[HN + c],  bn = bhh[2*HN + c];
    const float biR = bih[c], biZ = bih[HN + c], biN = bih[2*HN + c];
    float hprev = 0.f;                  // lanes<32: chain (lane>>4)

    if (g < 2*HN) ((unsigned short*)hSh)[g] = 0;
    int cur = 0;

    // ---- prologue: stage panel 0 ----
    STAGE(0);
    __syncthreads();

    for (int p0 = 0; p0 < VN; p0 += TP) {
        const bool hasnext = (p0 + TP) < VN;

        // ---- phase A region 1: writeback(p-1), eS(p), xi(p) from xS (B-frags from L2) ----
        if (p0 > 0) {
            int pp = p0 - TP;
            for (int idx = g; idx < 2*TP*32; idx += 512) {
                int rs = idx >> 9, j = idx & 511, t = j >> 5, c4 = j & 31;
                *(float4*)&x[((long)(a0 + rs*256)*VN + pp + t)*HN + c4*4] =
                    *(const float4*)&hOut[rs][t][c4*4];
            }
        }
        if (g < 32) eS[g >> 4][g & 15] = map[(long)(a0 + (g >> 4)*256)*VN + p0 + (g & 15)];
        {
            f32x4 xacc00 = Z4, xacc01 = Z4, xacc02 = Z4;
            f32x4 xacc10 = Z4, xacc11 = Z4, xacc12 = Z4;
            XI_PAIR(0,0); XI_PAIR(0,1); XI_PAIR(0,2); XI_PAIR(0,3);
            XI_PAIR(1,0); XI_PAIR(1,1); XI_PAIR(1,2); XI_PAIR(1,3);
            XI_PAIR(2,0); XI_PAIR(2,1); XI_PAIR(2,2); XI_PAIR(2,3);
            XI_STORE();
        }
        __syncthreads();

        // ---- phase A region 2: stage x(p+1), corr gather into xiP(p) ----
        if (hasnext) STAGE(p0 + TP);
        CORR_ADD();
        __syncthreads();

        // ---- 16 gate steps (pure LDS/MFMA/VALU) ----
        STEP(0);  STEP(1);  STEP(2);  STEP(3);
        STEP(4);  STEP(5);  STEP(6);  STEP(7);
        STEP(8);  STEP(9);  STEP(10); STEP(11);
        STEP(12); STEP(13); STEP(14); STEP(15);
    }
    // ---- final write-back ----
    {
        int pp = VN - TP;
        for (int idx = g; idx < 2*TP*32; idx += 512) {
            int rs = idx >> 9, j = idx & 511, t = j >> 5, c4 = j & 31;
            *(float4*)&x[((long)(a0 + rs*256)*VN + pp + t)*HN + c4*4] =
                *(const float4*)&hOut[rs][t][c4*4];
        }
    }
}

extern "C" void kernel_launch(void* const* d_in, const int* in_sizes, int n_in,
                              void* d_out, int out_size, void* d_ws, size_t ws_size,
                              hipStream_t stream) {
    const float* adj   = (const float*)d_in[0];
    const void*  edges = d_in[1];
    const float* emb   = (const float*)d_in[2];
    const float* w1    = (const float*)d_in[3];
    const float* w2    = (const float*)d_in[4];
    const float* w3    = (const float*)d_in[5];
    const float* wih   = (const float*)d_in[6];
    const float* whh   = (const float*)d_in[7];
    const float* bih   = (const float*)d_in[8];
    const float* bhh   = (const float*)d_in[9];

    float* x = (float*)d_out;          // x lives in d_out; scan updates it in place

    char* p = (char*)d_ws;
    auto alloc = [&](size_t bytes) { char* r = p; p += (bytes + 255) & ~255UL; return r; };
    float* in3    = (float*)alloc((size_t)EN*G3*4);
    float* corr   = (float*)alloc((size_t)EN*G3*4);
    float* colsum = (float*)alloc((size_t)VN*HN*4);
    int*   nnz    = (int*)  alloc((size_t)VN*4);
    int*   map    = (int*)  alloc((size_t)NROWS*4);
    int*   uA     = (int*)  alloc((size_t)EN*4);
    int*   vA     = (int*)  alloc((size_t)EN*4);
    unsigned short* wsF = (unsigned short*)alloc((size_t)24*4*64*8*2);
    unsigned short* whF = (unsigned short*)alloc((size_t)24*4*64*8*2);
    unsigned short* wlF = (unsigned short*)alloc((size_t)24*4*64*8*2);
    unsigned short* wcF = (unsigned short*)alloc((size_t)3*8*12*64*8*2);

    k_edges<<<EN/256, 256, 0, stream>>>(edges, uA, vA);
    k_pack<<<(3*8*12*64*8 + 255)/256, 256, 0, stream>>>(w1, w2, w3, wih, whh,
        wsF, whF, wlF, wcF);
    k_fill<<<NROWS/256, 256, 0, stream>>>(map, -1, NROWS);
    k_map<<<EN/256, 256, 0, stream>>>(uA, vA, map);
    k_embed<<<NROWS/2, 256, 0, stream>>>(adj, emb, x);

    for (int l = 0; l < LN; l++) {
        k_colsum<<<VN, 512, 0, stream>>>(x, colsum, nnz);
        k_edgein<<<EN/4, 256, 0, stream>>>(x, uA, vA, colsum, nnz, in3);
        k_msgcorr<<<EN/16, 512, 0, stream>>>(in3, wcF + (long)l*8*12*64*8, wlF, corr);
        k_scanf<<<VN/2, 512, 0, stream>>>(x, wsF, whF, bih, bhh, corr, map);
    }
}

// Round 19
// 1295.725 us; speedup vs baseline: 2.0851x; 1.0907x over previous
//
#include <hip/hip_runtime.h>

#define VN 512
#define EN 32768
#define FN 8
#define HN 128
#define G3 384
#define LN 3
#define TP 16
#define NROWS (VN*VN)   // 262144
#define XIPAD 388       // 4*388 % 32 == 16 -> 2-way LDS aliasing (free)

typedef _Float16 f16x8 __attribute__((ext_vector_type(8)));
typedef float f32x4  __attribute__((ext_vector_type(4)));

__device__ __forceinline__ unsigned short f2h(float f) {
    _Float16 h = (_Float16)f;
    return __builtin_bit_cast(unsigned short, h);
}
__device__ __forceinline__ float h2f(unsigned short u) {
    return (float)__builtin_bit_cast(_Float16, u);
}
__device__ __forceinline__ float fexp2(float x) {
    float r; asm("v_exp_f32 %0, %1" : "=v"(r) : "v"(x)); return r;
}
__device__ __forceinline__ float frcp(float x) {
    float r; asm("v_rcp_f32 %0, %1" : "=v"(r) : "v"(x)); return r;
}
__device__ __forceinline__ float fsigmoid(float x) {
    return frcp(1.f + fexp2(x * -1.44269504089f));
}
__device__ __forceinline__ float ftanh(float x) {
    return 1.f - 2.f * frcp(1.f + fexp2(x * 2.88539008178f));
}

// ---------------- generic int fill ----------------
__global__ void k_fill(int* __restrict__ p, int val, int n) {
    int i = blockIdx.x * 256 + threadIdx.x;
    if (i < n) p[i] = val;
}

// ---------------- edge canonicalize (+ int64 detection) ----------------
__global__ void k_edges(const void* __restrict__ raw, int* __restrict__ uo, int* __restrict__ vo) {
    const int* r32 = (const int*)raw;
    const long long* r64 = (const long long*)raw;
    int acc = 0;
    #pragma unroll
    for (int i = 1; i < 128; i += 2) acc |= r32[i];
    bool is64 = (acc == 0);
    int e = blockIdx.x * 256 + threadIdx.x;
    if (e < EN) {
        int u, v;
        if (is64) { u = (int)r64[2*e]; v = (int)r64[2*e+1]; }
        else      { u = r32[2*e];      v = r32[2*e+1]; }
        uo[e] = u; vo[e] = v;
    }
}

// ---------------- pack weight B-fragments (single f16, MFMA lane layout) ----------------
// frag layout: [..ntile..][ktile][lane][elem]: k = kt*32 + (lane>>4)*8 + e ; col = nt*16 + (lane&15)
__global__ void k_pack(const float* __restrict__ w1, const float* __restrict__ w2,
                       const float* __restrict__ w3, const float* __restrict__ wih,
                       const float* __restrict__ whh,
                       unsigned short* __restrict__ wsF, unsigned short* __restrict__ whF,
                       unsigned short* __restrict__ wlF, unsigned short* __restrict__ wcF) {
    int t = blockIdx.x * 256 + threadIdx.x;
    if (t < 3*8*12*64*8) {        // wcat frags [l][nt0..7][kt0..11]
        int e = t & 7, lane = (t >> 3) & 63;
        int frag = t >> 9;
        int kt = frag % 12;
        int rem = frag / 12;
        int nt = rem & 7;
        int l  = rem >> 3;
        int k  = kt*32 + (lane >> 4)*8 + e;
        int gc = nt*16 + (lane & 15);
        const float* w = (k < 128) ? w1 : (k < 256 ? w2 : w3);
        wcF[t] = f2h(w[((long)l*128 + gc)*128 + (k & 127)]);
    }
    if (t < 24*4*64*8) {          // wsum / whh / wl frags [nt0..23][kt0..3]
        int e = t & 7, lane = (t >> 3) & 63, kt = (t >> 9) & 3, nt = t >> 11;
        int k  = kt*32 + (lane >> 4)*8 + e;
        int gc = nt*16 + (lane & 15);
        wsF[t] = f2h(wih[gc*256 + k] + wih[gc*256 + 128 + k]);
        whF[t] = f2h(whh[gc*HN + k]);
        wlF[t] = f2h(wih[gc*256 + k]);
    }
}

// ---------------- winner map ----------------
__global__ void k_map(const int* __restrict__ uA, const int* __restrict__ vA, int* __restrict__ map) {
    int e = blockIdx.x * 256 + threadIdx.x;
    if (e < EN) atomicMax(&map[uA[e]*VN + vA[e]], e);
}

// ---------------- embed ----------------
__global__ __launch_bounds__(256) void k_embed(const float* __restrict__ adj,
                                               const float* __restrict__ emb,
                                               float* __restrict__ x) {
    __shared__ float semb[HN][FN];
    __shared__ float sadj[2][FN];
    int tid = threadIdx.x;
    for (int i = tid; i < HN*FN; i += 256) semb[i/FN][i%FN] = emb[i];
    if (tid < 16) sadj[tid>>3][tid&7] = adj[(long)blockIdx.x*16 + tid];
    __syncthreads();
    int p = tid >> 7;
    int h = tid & 127;
    float acc = 0.f;
    #pragma unroll
    for (int f = 0; f < FN; f++) acc += sadj[p][f]*semb[h][f];
    long row = (long)blockIdx.x*2 + p;
    x[row*HN + h] = acc;
}

// ---------------- colsum + nnz ----------------
__global__ __launch_bounds__(512) void k_colsum(const float* __restrict__ x,
                                                float* __restrict__ colsum, int* __restrict__ nnz) {
    int b = blockIdx.x;
    int tid = threadIdx.x;
    int h = tid & 127, q = tid >> 7;
    float s = 0.f; int c = 0;
    for (int a = q*128; a < q*128 + 128; a++) {
        float v = x[((long)a*VN + b)*HN + h];
        s += v; c += (v != 0.f) ? 1 : 0;
    }
    __shared__ float ss[4][128];
    __shared__ int sc[8];
    ss[q][h] = s;
    #pragma unroll
    for (int off = 32; off; off >>= 1) c += __shfl_down(c, off);
    if ((tid & 63) == 0) sc[tid>>6] = c;
    __syncthreads();
    if (tid < 128) colsum[b*HN + tid] = ss[0][tid]+ss[1][tid]+ss[2][tid]+ss[3][tid];
    if (tid == 0) { int t = 0; for (int i = 0; i < 8; i++) t += sc[i]; nnz[b] = t; }
}

#define MF16(A,B,C) __builtin_amdgcn_mfma_f32_16x16x32_f16((A),(B),(C),0,0,0)
#define Z4 ((f32x4){0.f,0.f,0.f,0.f})

// ================= fused edgein + msg + corr (f16 MFMA) =================
// 2048 blocks x 512 threads; block owns 16 edges. Phase 0: one wave per 2 edges
// computes in3 rows [x_uv, e_in, e_out] directly into LDS as f16 hi/lo pairs
// (XOR-swizzled 8-elem groups). Phase 1: msg = relu(in3 @ Wcat^T) with A-frags
// from LDS; D = msg - x_uv (f16-pair reconstruction). Phase 2: corr = D @ Wl^T.
// Eliminates the 50 MB in3 global round-trip per layer.
__global__ __launch_bounds__(512) void k_fused(
    const float* __restrict__ x,
    const int* __restrict__ uA, const int* __restrict__ vA,
    const float* __restrict__ colsum, const int* __restrict__ nnz,
    const unsigned short* __restrict__ wcF, const unsigned short* __restrict__ wlF,
    float* __restrict__ corr) {
    const int g = threadIdx.x;
    const int wv = g >> 6;
    const int lane = g & 63;
    const int r16 = lane & 15;
    const int kgrp = lane >> 4;
    const long m0 = (long)blockIdx.x * 16;

    __shared__ unsigned short i3h[16][G3];      // 12.3 KB, swizzled groups
    __shared__ unsigned short i3l[16][G3];      // 12.3 KB
    __shared__ unsigned short Dh[16][136];
    __shared__ unsigned short Dl[16][136];

    // ---- phase 0: edge inputs -> LDS (f16 hi/lo, swizzled) ----
    #pragma unroll
    for (int ei = 0; ei < 2; ei++) {
        const int row = wv*2 + ei;          // 0..15
        const int e = (int)m0 + row;
        int u = uA[e], v = vA[e];
        const float* xuv = x + ((long)u*VN + v)*HN;
        const float* xvu = x + ((long)v*VN + u)*HN;
        float xu0 = xuv[lane], xu1 = xuv[lane+64];
        float xv0 = xvu[lane], xv1 = xvu[lane+64];
        int cnt_vu = __popcll(__ballot(xv0 != 0.f)) + __popcll(__ballot(xv1 != 0.f));
        int cnt_uv = __popcll(__ballot(xu0 != 0.f)) + __popcll(__ballot(xu1 != 0.f));
        float nin  = (float)(nnz[u] - cnt_vu) * (1.f/128.f); if (nin  == 0.f) nin  = 1.f;
        float nout = (float)(nnz[v] - cnt_uv) * (1.f/128.f); if (nout == 0.f) nout = 1.f;
        float vals[6];
        int   ks[6];
        vals[0] = xu0;                                 ks[0] = lane;
        vals[1] = xu1;                                 ks[1] = lane + 64;
        vals[2] = (colsum[u*HN+lane]    - xv0)/nin;    ks[2] = 128 + lane;
        vals[3] = (colsum[u*HN+lane+64] - xv1)/nin;    ks[3] = 128 + lane + 64;
        vals[4] = (colsum[v*HN+lane]    - xu0)/nout;   ks[4] = 256 + lane;
        vals[5] = (colsum[v*HN+lane+64] - xu1)/nout;   ks[5] = 256 + lane + 64;
        #pragma unroll
        for (int j = 0; j < 6; j++) {
            int k = ks[j];
            int g8 = k >> 3;
            int addr = ((g8 & 48) | ((g8 & 15) ^ row))*8 + (k & 7);
            unsigned short hi = f2h(vals[j]);
            i3h[row][addr] = hi;
            i3l[row][addr] = f2h(vals[j] - h2f(hi));
        }
    }
    __syncthreads();

    // ---- phase 1: msg = relu(in3 @ Wcat^T); D = msg - x_uv ----
    f32x4 pacc[2];
    pacc[0] = Z4; pacc[1] = Z4;
    #pragma unroll
    for (int kt = 0; kt < 12; kt++) {
        int g8 = kt*4 + kgrp;
        int addr = ((g8 & 48) | ((g8 & 15) ^ r16))*8;
        f16x8 ah = *(const f16x8*)&i3h[r16][addr];
        f16x8 al = *(const f16x8*)&i3l[r16][addr];
        f16x8 bF = *(const f16x8*)&wcF[(((long)wv*12 + kt)*64 + lane)*8];
        const int p = kt & 1;
        pacc[p] = MF16(ah, bF, pacc[p]);
        pacc[p] = MF16(al, bF, pacc[p]);
    }
    const int c = wv*16 + r16;                  // msg col 0..127
    {
        int g8c = c >> 3;                       // 0..15
        #pragma unroll
        for (int r = 0; r < 4; r++) {
            int m = kgrp*4 + r;
            int addr = ((g8c ^ m) & 15)*8 + (c & 7);
            float xuv_v = h2f(i3h[m][addr]) + h2f(i3l[m][addr]);
            float mv = fmaxf(pacc[0][r] + pacc[1][r], 0.f) - xuv_v;
            unsigned short hi = f2h(mv);
            Dh[m][c] = hi;
            Dl[m][c] = f2h(mv - h2f(hi));
        }
    }
    __syncthreads();

    // ---- phase 2: corr = D @ Wl^T ----
    f32x4 cacc[3];
    cacc[0] = cacc[1] = cacc[2] = Z4;
    #pragma unroll
    for (int kt = 0; kt < 4; kt++) {
        f16x8 ah = *(const f16x8*)&Dh[r16][kt*32 + kgrp*8];
        f16x8 al = *(const f16x8*)&Dl[r16][kt*32 + kgrp*8];
        #pragma unroll
        for (int j = 0; j < 3; j++) {
            f16x8 bF = *(const f16x8*)&wlF[(((long)(wv*3 + j)*4 + kt)*64 + lane)*8];
            cacc[j] = MF16(ah, bF, cacc[j]);
            cacc[j] = MF16(al, bF, cacc[j]);
        }
    }
    #pragma unroll
    for (int j = 0; j < 3; j++) {
        int n = (wv*3 + j)*16 + r16;
        #pragma unroll
        for (int r = 0; r < 4; r++)
            corr[(m0 + kgrp*4 + r)*G3 + n] = cacc[j][r];
    }
}

// ================= fused xi(f16 MFMA, phase-A) + GRU scan (r15 configuration) =================
// 256 blocks x 512 threads (8 waves); block owns chains {a0, a0+256}.
// Best measured config (r15/r18: scanf 350us): h single-f16 (12 gh MFMA/wave/step),
// ds_swizzle xor-16 cross-chain move, phase-A xi with wsF streamed from L2,
// wH-only resident (48 VGPRs), no clamp. Steps pure LDS/MFMA/VALU, 1 barrier each.

// stage x rows [ROWBASE, ROWBASE+16) of both chains into xS (f16 hi, 4-bit XOR swizzle)
#define STAGE(ROWBASE) do { \
    int rs_ = g >> 8, row_ = (g >> 4) & 15, cg_ = g & 15; \
    const float* xs_ = &x[((long)(a0 + rs_*256)*VN + (ROWBASE) + row_)*HN + cg_*8]; \
    float4 v0_ = *(const float4*)xs_; \
    float4 v1_ = *(const float4*)(xs_ + 4); \
    f16x8 H_; \
    H_[0] = (_Float16)v0_.x; H_[1] = (_Float16)v0_.y; \
    H_[2] = (_Float16)v0_.z; H_[3] = (_Float16)v0_.w; \
    H_[4] = (_Float16)v1_.x; H_[5] = (_Float16)v1_.y; \
    H_[6] = (_Float16)v1_.z; H_[7] = (_Float16)v1_.w; \
    int slot_ = cg_ ^ row_; \
    *(f16x8*)&xSh[rs_][row_][slot_*8] = H_; \
} while(0)

// xi item pair (both chains share one B-frag load from L2)
#define XI_PAIR(GI, KT) do { \
    f16x8 bF_ = *(const f16x8*)&wsF[(((long)((GI)*8 + wv)*4 + (KT))*64 + lane)*8]; \
    int slot_ = ((KT)*4 + kgrp) ^ r16; \
    f16x8 A0_ = *(const f16x8*)&xSh[0][r16][slot_*8]; \
    f16x8 A1_ = *(const f16x8*)&xSh[1][r16][slot_*8]; \
    xacc0##GI = MF16(A0_, bF_, xacc0##GI); \
    xacc1##GI = MF16(A1_, bF_, xacc1##GI); \
} while(0)

#define XI_STORE() do { \
    _Pragma("unroll") \
    for (int r_ = 0; r_ < 4; ++r_) { \
        xiP[0][kgrp*4 + r_][c]        = xacc00[r_] + biR; \
        xiP[0][kgrp*4 + r_][HN + c]   = xacc01[r_] + biZ; \
        xiP[0][kgrp*4 + r_][2*HN + c] = xacc02[r_] + biN; \
        xiP[1][kgrp*4 + r_][c]        = xacc10[r_] + biR; \
        xiP[1][kgrp*4 + r_][HN + c]   = xacc11[r_] + biZ; \
        xiP[1][kgrp*4 + r_][2*HN + c] = xacc12[r_] + biN; \
    } \
} while(0)

#define CORR_ADD() do { if (g < G3) { \
    for (int rs_ = 0; rs_ < 2; ++rs_) \
        for (int t_ = 0; t_ < TP; ++t_) { \
            int e_ = eS[rs_][t_]; \
            if (e_ >= 0) xiP[rs_][t_][g] += corr[(long)e_*G3 + g]; \
        } } } while(0)

#define STEP(T) do { \
    const int arow_ = r16 & 1; \
    f16x8 hA0_ = *(const f16x8*)&hSh[cur][arow_][0*32 + kgrp*8]; \
    f16x8 hA1_ = *(const f16x8*)&hSh[cur][arow_][1*32 + kgrp*8]; \
    f16x8 hA2_ = *(const f16x8*)&hSh[cur][arow_][2*32 + kgrp*8]; \
    f16x8 hA3_ = *(const f16x8*)&hSh[cur][arow_][3*32 + kgrp*8]; \
    f32x4 gr0_ = Z4, gr1_ = Z4, gz0_ = Z4, gz1_ = Z4, gn0_ = Z4, gn1_ = Z4; \
    __builtin_amdgcn_s_setprio(1); \
    gr0_ = MF16(hA0_, wH[0], gr0_); \
    gr1_ = MF16(hA1_, wH[1], gr1_); \
    gr0_ = MF16(hA2_, wH[2], gr0_); \
    gr1_ = MF16(hA3_, wH[3], gr1_); \
    gz0_ = MF16(hA0_, wH[4], gz0_); \
    gz1_ = MF16(hA1_, wH[5], gz1_); \
    gz0_ = MF16(hA2_, wH[6], gz0_); \
    gz1_ = MF16(hA3_, wH[7], gz1_); \
    gn0_ = MF16(hA0_, wH[8], gn0_); \
    gn1_ = MF16(hA1_, wH[9], gn1_); \
    gn0_ = MF16(hA2_, wH[10], gn0_); \
    gn1_ = MF16(hA3_, wH[11], gn1_); \
    __builtin_amdgcn_s_setprio(0); \
    float sR_ = gr0_[0] + gr1_[0], tR_ = gr0_[1] + gr1_[1]; \
    float sZ_ = gz0_[0] + gz1_[0], tZ_ = gz0_[1] + gz1_[1]; \
    float sN_ = gn0_[0] + gn1_[0], tN_ = gn0_[1] + gn1_[1]; \
    float mR_ = __int_as_float(__builtin_amdgcn_ds_swizzle(__float_as_int(tR_), 0x401F)); \
    float mZ_ = __int_as_float(__builtin_amdgcn_ds_swizzle(__float_as_int(tZ_), 0x401F)); \
    float mN_ = __int_as_float(__builtin_amdgcn_ds_swizzle(__float_as_int(tN_), 0x401F)); \
    float vR_ = (lane < 16) ? sR_ : mR_; \
    float vZ_ = (lane < 16) ? sZ_ : mZ_; \
    float vN_ = (lane < 16) ? sN_ : mN_; \
    if (lane < 32) { \
        int rs_ = lane >> 4; \
        float xr_ = xiP[rs_][T][c]; \
        float xz_ = xiP[rs_][T][HN + c]; \
        float xn_ = xiP[rs_][T][2*HN + c]; \
        float r_ = fsigmoid(xr_ + vR_ + br); \
        float z_ = fsigmoid(xz_ + vZ_ + bz); \
        float n_ = ftanh(xn_ + r_*(vN_ + bn)); \
        float h_ = (1.f - z_)*n_ + z_*hprev; \
        hprev = h_; \
        hOut[rs_][T][c] = h_; \
        hSh[cur ^ 1][rs_][c] = f2h(h_); \
    } \
    cur ^= 1; \
    __syncthreads(); \
} while(0)

__global__ __launch_bounds__(512) void k_scanf(
    float* __restrict__ x,
    const unsigned short* __restrict__ wsF, const unsigned short* __restrict__ whF,
    const float* __restrict__ bih, const float* __restrict__ bhh,
    const float* __restrict__ corr, const int* __restrict__ map) {
    const int g = threadIdx.x;
    const int a0 = blockIdx.x;
    const int wv = g >> 6;
    const int lane = g & 63;
    const int r16 = lane & 15;
    const int kgrp = lane >> 4;

    __shared__ float xiP[2][TP][XIPAD];             // 49.7 KB [chain][t][col3]
    __shared__ unsigned short xSh[2][TP][HN];       // 8 KB (chain, row, swz col) -- hi only
    __shared__ unsigned short hSh[2][2][HN];        // [parity][chain][col] 1 KB -- f16 single
    __shared__ float hOut[2][TP][HN];               // 16 KB
    __shared__ int eS[2][TP];                       // total ~74.9 KB

    // resident whh B-frags only (48 VGPRs); wsF streamed in phase A
    f16x8 wH[12];
    #pragma unroll
    for (int gi = 0; gi < 3; gi++)
        #pragma unroll
        for (int kt = 0; kt < 4; kt++) {
            long bidx = (((long)(gi*8 + wv)*4 + kt)*64 + lane)*8;
            wH[gi*4+kt] = *(const f16x8*)&whF[bidx];
        }

    const int c = wv*16 + r16;
    const float br = bhh[c],  bz = bhh[HN + c],  bn = bhh[2*HN + c];
    const float biR = bih[c], biZ = bih[HN + c], biN = bih[2*HN + c];
    float hprev = 0.f;                  // lanes<32: chain (lane>>4)

    if (g < 2*HN) ((unsigned short*)hSh)[g] = 0;
    int cur = 0;

    // ---- prologue: stage panel 0 ----
    STAGE(0);
    __syncthreads();

    for (int p0 = 0; p0 < VN; p0 += TP) {
        const bool hasnext = (p0 + TP) < VN;

        // ---- phase A region 1: writeback(p-1), eS(p), xi(p) from xS (B-frags from L2) ----
        if (p0 > 0) {
            int pp = p0 - TP;
            for (int idx = g; idx < 2*TP*32; idx += 512) {
                int rs = idx >> 9, j = idx & 511, t = j >> 5, c4 = j & 31;
                *(float4*)&x[((long)(a0 + rs*256)*VN + pp + t)*HN + c4*4] =
                    *(const float4*)&hOut[rs][t][c4*4];
            }
        }
        if (g < 32) eS[g >> 4][g & 15] = map[(long)(a0 + (g >> 4)*256)*VN + p0 + (g & 15)];
        {
            f32x4 xacc00 = Z4, xacc01 = Z4, xacc02 = Z4;
            f32x4 xacc10 = Z4, xacc11 = Z4, xacc12 = Z4;
            XI_PAIR(0,0); XI_PAIR(0,1); XI_PAIR(0,2); XI_PAIR(0,3);
            XI_PAIR(1,0); XI_PAIR(1,1); XI_PAIR(1,2); XI_PAIR(1,3);
            XI_PAIR(2,0); XI_PAIR(2,1); XI_PAIR(2,2); XI_PAIR(2,3);
            XI_STORE();
        }
        __syncthreads();

        // ---- phase A region 2: stage x(p+1), corr gather into xiP(p) ----
        if (hasnext) STAGE(p0 + TP);
        CORR_ADD();
        __syncthreads();

        // ---- 16 gate steps (pure LDS/MFMA/VALU) ----
        STEP(0);  STEP(1);  STEP(2);  STEP(3);
        STEP(4);  STEP(5);  STEP(6);  STEP(7);
        STEP(8);  STEP(9);  STEP(10); STEP(11);
        STEP(12); STEP(13); STEP(14); STEP(15);
    }
    // ---- final write-back ----
    {
        int pp = VN - TP;
        for (int idx = g; idx < 2*TP*32; idx += 512) {
            int rs = idx >> 9, j = idx & 511, t = j >> 5, c4 = j & 31;
            *(float4*)&x[((long)(a0 + rs*256)*VN + pp + t)*HN + c4*4] =
                *(const float4*)&hOut[rs][t][c4*4];
        }
    }
}

extern "C" void kernel_launch(void* const* d_in, const int* in_sizes, int n_in,
                              void* d_out, int out_size, void* d_ws, size_t ws_size,
                              hipStream_t stream) {
    const float* adj   = (const float*)d_in[0];
    const void*  edges = d_in[1];
    const float* emb   = (const float*)d_in[2];
    const float* w1    = (const float*)d_in[3];
    const float* w2    = (const float*)d_in[4];
    const float* w3    = (const float*)d_in[5];
    const float* wih   = (const float*)d_in[6];
    const float* whh   = (const float*)d_in[7];
    const float* bih   = (const float*)d_in[8];
    const float* bhh   = (const float*)d_in[9];

    float* x = (float*)d_out;          // x lives in d_out; scan updates it in place

    char* p = (char*)d_ws;
    auto alloc = [&](size_t bytes) { char* r = p; p += (bytes + 255) & ~255UL; return r; };
    float* corr   = (float*)alloc((size_t)EN*G3*4);
    float* colsum = (float*)alloc((size_t)VN*HN*4);
    int*   nnz    = (int*)  alloc((size_t)VN*4);
    int*   map    = (int*)  alloc((size_t)NROWS*4);
    int*   uA     = (int*)  alloc((size_t)EN*4);
    int*   vA     = (int*)  alloc((size_t)EN*4);
    unsigned short* wsF = (unsigned short*)alloc((size_t)24*4*64*8*2);
    unsigned short* whF = (unsigned short*)alloc((size_t)24*4*64*8*2);
    unsigned short* wlF = (unsigned short*)alloc((size_t)24*4*64*8*2);
    unsigned short* wcF = (unsigned short*)alloc((size_t)3*8*12*64*8*2);

    k_edges<<<EN/256, 256, 0, stream>>>(edges, uA, vA);
    k_pack<<<(3*8*12*64*8 + 255)/256, 256, 0, stream>>>(w1, w2, w3, wih, whh,
        wsF, whF, wlF, wcF);
    k_fill<<<NROWS/256, 256, 0, stream>>>(map, -1, NROWS);
    k_map<<<EN/256, 256, 0, stream>>>(uA, vA, map);
    k_embed<<<NROWS/2, 256, 0, stream>>>(adj, emb, x);

    for (int l = 0; l < LN; l++) {
        k_colsum<<<VN, 512, 0, stream>>>(x, colsum, nnz);
        k_fused<<<EN/16, 512, 0, stream>>>(x, uA, vA, colsum, nnz,
                                           wcF + (long)l*8*12*64*8, wlF, corr);
        k_scanf<<<VN/2, 512, 0, stream>>>(x, wsF, whF, bih, bhh, corr, map);
    }
}